// Round 6
// baseline (79.121 us; speedup 1.0000x reference)
//
#include <hip/hip_runtime.h>
#include <hip/hip_bf16.h>
#include <math.h>
#include <stdint.h>

#define B_ 4
#define S_ 2048
#define DM_ 512
#define H_ 8
#define DH_ 64
#define DOUT_ 512
#define W_ 8
#define NS_ 2
#define T_ (NS_ + S_)      // 2050 rows per batch in xc
#define M_TOT (B_ * T_)    // 8200
#define M_PAD 8320         // 65 * 128 (grid only; pad rows staged as zero)
#define N3 1536            // q | k | v concatenated columns
#define SCHUNK 16          // s-strip per thread in attn

typedef __attribute__((ext_vector_type(8))) __bf16   bf16x8;
typedef __attribute__((ext_vector_type(4))) float    f32x4;
typedef __attribute__((ext_vector_type(8))) uint16_t u16x8;

__device__ inline uint16_t f2bf(float f) {          // RNE f32 -> bf16
    uint32_t u = __builtin_bit_cast(uint32_t, f);
    u += 0x7FFF + ((u >> 16) & 1);
    return (uint16_t)(u >> 16);
}
__device__ inline float bf2f(uint16_t u) {
    return __builtin_bit_cast(float, (uint32_t)u << 16);
}

// ---------------------------------------------------------------------------
// convB: Bt[n][k] = W(n)[k][n%512] in bf16  (transpose + convert via LDS tile)
// ---------------------------------------------------------------------------
__global__ __launch_bounds__(256) void convB(
    const float* __restrict__ Wq, const float* __restrict__ Wk,
    const float* __restrict__ Wv, uint16_t* __restrict__ Bt)
{
    __shared__ float tile[32][65];
    const int n0 = blockIdx.x * 64, k0 = blockIdx.y * 32;
    const float* Wsrc = (n0 < 512) ? Wq : ((n0 < 1024) ? Wk : Wv);
    const int nb = n0 & 511;
    const int tid = threadIdx.x;
    const int nn = tid & 63, kk = tid >> 6;          // kk 0..3
    #pragma unroll
    for (int i = 0; i < 8; ++i)
        tile[kk + i * 4][nn] = Wsrc[(size_t)(k0 + kk + i * 4) * DOUT_ + nb + nn];
    __syncthreads();
    const int nn2 = tid >> 2, k8 = (tid & 3) * 8;
    u16x8 o;
    #pragma unroll
    for (int j = 0; j < 8; ++j) o[j] = f2bf(tile[k8 + j][nn2]);
    *(u16x8*)&Bt[(size_t)(n0 + nn2) * DM_ + k0 + k8] = o;
}

// ---------------------------------------------------------------------------
// gemm_bf16: y[M][N3](bf16) = xc[M][512] * Bt[N3][512]^T (+bk on k third)
// A reg-staged from f32 x/sink (convert in-reg, swizzled ds_write_b128);
// B via global_load_lds w=16 (linear dest, inverse-swizzled source).
// 128x128 tile, BK=32, 4 waves (2x2), 16x16x32 MFMA.
// ---------------------------------------------------------------------------
__global__ __launch_bounds__(256) void gemm_bf16(
    const float* __restrict__ x, const float* __restrict__ sink,
    const uint16_t* __restrict__ Bt, const float* __restrict__ bk,
    uint16_t* __restrict__ y)
{
    __shared__ __align__(16) uint16_t As[128 * 32];
    __shared__ __align__(16) uint16_t Bs[128 * 32];
    const int tid  = threadIdx.x;
    const int wave = tid >> 6, lane = tid & 63;
    const int row0 = blockIdx.y * 128, col0 = blockIdx.x * 128;
    const int wm = wave >> 1, wn = wave & 1;         // 2x2 wave grid
    f32x4 acc[4][4] = {};

    const int srow  = tid >> 2;                      // staging row 0..63
    const int sslot = tid & 3;                       // 8-elem slot in row

    // per-thread A-row pointers (rows srow and srow+64), computed once
    const float* aptr0 = nullptr; const float* aptr1 = nullptr;
    {
        int row = row0 + srow;
        if (row < M_TOT) {
            int b = row / T_, t = row - b * T_;
            aptr0 = (t < NS_) ? sink + ((size_t)b * NS_ + t) * DM_
                              : x    + ((size_t)b * S_  + (t - NS_)) * DM_;
        }
        row = row0 + 64 + srow;
        if (row < M_TOT) {
            int b = row / T_, t = row - b * T_;
            aptr1 = (t < NS_) ? sink + ((size_t)b * NS_ + t) * DM_
                              : x    + ((size_t)b * S_  + (t - NS_)) * DM_;
        }
    }
    // swizzled A slot (same ((r>>1)&3) XOR as the read side; r=srow and
    // r=srow+64 give the same value since 64>>1 is 0 mod 4)
    const int ssw = sslot ^ ((srow >> 1) & 3);

    for (int k0 = 0; k0 < DM_; k0 += 32) {
        // ---- stage A: f32 load -> bf16 convert -> swizzled ds_write ----
        {
            u16x8 a0 = (u16x8)0, a1 = (u16x8)0;
            if (aptr0) {
                float4 f0 = *(const float4*)(aptr0 + k0 + sslot * 8);
                float4 f1 = *(const float4*)(aptr0 + k0 + sslot * 8 + 4);
                a0[0] = f2bf(f0.x); a0[1] = f2bf(f0.y); a0[2] = f2bf(f0.z); a0[3] = f2bf(f0.w);
                a0[4] = f2bf(f1.x); a0[5] = f2bf(f1.y); a0[6] = f2bf(f1.z); a0[7] = f2bf(f1.w);
            }
            if (aptr1) {
                float4 f0 = *(const float4*)(aptr1 + k0 + sslot * 8);
                float4 f1 = *(const float4*)(aptr1 + k0 + sslot * 8 + 4);
                a1[0] = f2bf(f0.x); a1[1] = f2bf(f0.y); a1[2] = f2bf(f0.z); a1[3] = f2bf(f0.w);
                a1[4] = f2bf(f1.x); a1[5] = f2bf(f1.y); a1[6] = f2bf(f1.z); a1[7] = f2bf(f1.w);
            }
            *(u16x8*)&As[(srow)      * 32 + ssw * 8] = a0;
            *(u16x8*)&As[(srow + 64) * 32 + ssw * 8] = a1;
        }
        // ---- stage B: global_load_lds, inverse-swizzled global source ----
        #pragma unroll
        for (int i = 0; i < 2; ++i) {
            const int r  = i * 64 + srow;
            const int ls = sslot ^ ((r >> 1) & 3);
            const uint16_t* gb = Bt + (size_t)(col0 + r) * DM_ + k0 + ls * 8;
            __builtin_amdgcn_global_load_lds(
                (const __attribute__((address_space(1))) void*)gb,
                (__attribute__((address_space(3))) void*)(Bs + i * 2048 + wave * 512),
                16, 0, 0);
        }
        __syncthreads();

        const int kslot = lane >> 4;                 // which 8-wide k slice
        const int fr    = lane & 15;
        bf16x8 af[4], bfr[4];
        #pragma unroll
        for (int mi = 0; mi < 4; ++mi) {
            const int r  = wm * 64 + mi * 16 + fr;
            const int ss = kslot ^ ((r >> 1) & 3);
            af[mi] = *(const bf16x8*)&As[r * 32 + ss * 8];
        }
        #pragma unroll
        for (int ni = 0; ni < 4; ++ni) {
            const int r  = wn * 64 + ni * 16 + fr;
            const int ss = kslot ^ ((r >> 1) & 3);
            bfr[ni] = *(const bf16x8*)&Bs[r * 32 + ss * 8];
        }
        #pragma unroll
        for (int mi = 0; mi < 4; ++mi)
            #pragma unroll
            for (int ni = 0; ni < 4; ++ni)
                acc[mi][ni] = __builtin_amdgcn_mfma_f32_16x16x32_bf16(
                    af[mi], bfr[ni], acc[mi][ni], 0, 0, 0);
        __syncthreads();
    }

    // epilogue: C row = (lane>>4)*4 + reg, col = lane&15; store bf16
    const int fr = lane & 15, fq = lane >> 4;
    #pragma unroll
    for (int ni = 0; ni < 4; ++ni) {
        const int col = col0 + wn * 64 + ni * 16 + fr;
        const float bias = (col >= 512 && col < 1024) ? bk[col - 512] : 0.f;
        #pragma unroll
        for (int mi = 0; mi < 4; ++mi) {
            #pragma unroll
            for (int r4 = 0; r4 < 4; ++r4) {
                const int row = row0 + wm * 64 + mi * 16 + fq * 4 + r4;
                if (row < M_TOT)
                    y[(size_t)row * N3 + col] = f2bf(acc[mi][ni][r4] + bias);
            }
        }
    }
}

// ---------------------------------------------------------------------------
// attn: sliding-window over bf16 y. Thread = (b, c), strip of SCHUNK s.
// Ring of 8 q/v in registers: 3 new bf16 loads per s.
// ---------------------------------------------------------------------------
__global__ __launch_bounds__(512) void attn_kernel(
    const uint16_t* __restrict__ y, const float* __restrict__ pos,
    float* __restrict__ out)
{
    __shared__ float spos[DH_ * (NS_ + W_)];
    for (int i = threadIdx.x; i < DH_ * (NS_ + W_); i += 512) spos[i] = pos[i];
    __syncthreads();

    const int c  = threadIdx.x;                 // channel 0..511
    const int b  = blockIdx.y;
    const int s0 = blockIdx.x * SCHUNK;
    const uint16_t* yb = y + (size_t)b * T_ * N3;
    const int dh = c & (DH_ - 1);

    float pp[NS_ + W_];
    #pragma unroll
    for (int p = 0; p < NS_ + W_; ++p) pp[p] = spos[dh * (NS_ + W_) + p];

    const float sq0 = bf2f(yb[0 * N3 + c]),        sq1 = bf2f(yb[1 * N3 + c]);
    const float sv0 = bf2f(yb[0 * N3 + 1024 + c]), sv1 = bf2f(yb[1 * N3 + 1024 + c]);

    float qr[W_], vr[W_];
    #pragma unroll
    for (int j = 0; j < W_ - 1; ++j) {
        const uint16_t* rq = yb + (size_t)(NS_ + s0 + j) * N3 + c;
        qr[j] = bf2f(rq[0]);
        vr[j] = bf2f(rq[1024]);
    }

    for (int i = 0; i < SCHUNK; ++i) {
        const int s = s0 + i;
        int tq = NS_ + s + (W_ - 1);
        if (tq > T_ - 1) tq = T_ - 1;            // clamp (masked below)
        const uint16_t* rq = yb + (size_t)tq * N3 + c;
        qr[W_ - 1] = bf2f(rq[0]);
        vr[W_ - 1] = bf2f(rq[1024]);
        const float kv = bf2f(yb[(size_t)(NS_ + s) * N3 + 512 + c]);

        float sc[NS_ + W_];
        sc[0] = (sq0 + pp[0]) * kv;
        sc[1] = (sq1 + pp[1]) * kv;
        #pragma unroll
        for (int r = 0; r < W_; ++r) sc[NS_ + r] = (qr[r] + pp[NS_ + r]) * kv;
        if (s > S_ - W_) {                       // tail masking (uniform)
            const int nv = S_ - s;
            #pragma unroll
            for (int r = 0; r < W_; ++r)
                if (r >= nv) sc[NS_ + r] = -INFINITY;
        }

        float m = sc[0];
        #pragma unroll
        for (int p = 1; p < NS_ + W_; ++p) m = fmaxf(m, sc[p]);
        float e[NS_ + W_], sum = 0.f;
        #pragma unroll
        for (int p = 0; p < NS_ + W_; ++p) { e[p] = __expf(sc[p] - m); sum += e[p]; }
        float accv = e[0] * sv0 + e[1] * sv1;
        #pragma unroll
        for (int r = 0; r < W_; ++r) accv = fmaf(e[NS_ + r], vr[r], accv);

        out[((size_t)b * S_ + s) * DOUT_ + c] = accv / sum;

        #pragma unroll
        for (int j = 0; j < W_ - 1; ++j) { qr[j] = qr[j + 1]; vr[j] = vr[j + 1]; }
    }
}

// ---------------------------------------------------------------------------
extern "C" void kernel_launch(void* const* d_in, const int* in_sizes, int n_in,
                              void* d_out, int out_size, void* d_ws, size_t ws_size,
                              hipStream_t stream) {
    const float* x    = (const float*)d_in[0];
    const float* sink = (const float*)d_in[1];
    const float* Wk   = (const float*)d_in[2];
    const float* bk   = (const float*)d_in[3];
    const float* Wq   = (const float*)d_in[4];
    const float* Wv   = (const float*)d_in[5];
    const float* pos  = (const float*)d_in[6];

    char* ws = (char*)d_ws;
    uint16_t* y  = (uint16_t*)ws;                                 // 25,190,400 B
    uint16_t* Bt = (uint16_t*)(ws + (size_t)M_TOT * N3 * 2);      //  1,572,864 B

    convB<<<dim3(N3 / 64, DM_ / 32), 256, 0, stream>>>(Wq, Wk, Wv, Bt);
    gemm_bf16<<<dim3(N3 / 128, M_PAD / 128), 256, 0, stream>>>(x, sink, Bt, bk, y);
    attn_kernel<<<dim3(S_ / SCHUNK, B_), 512, 0, stream>>>(y, pos, (float*)d_out);
}

// Round 7
// 68.188 us; speedup vs baseline: 1.1603x; 1.1603x over previous
//
#include <hip/hip_runtime.h>
#include <hip/hip_bf16.h>
#include <math.h>
#include <stdint.h>

#define B_ 4
#define S_ 2048
#define DM_ 512
#define H_ 8
#define DH_ 64
#define DOUT_ 512
#define W_ 8
#define NS_ 2
#define T_ (NS_ + S_)      // 2050 rows per batch in xc
#define M_TOT (B_ * T_)    // 8200
#define M_PAD 8320         // 65 * 128, zero-padded tail
#define N3 1536            // q | k | v concatenated columns
#define SCHUNK 16          // s-strip per thread in attn

typedef __attribute__((ext_vector_type(8))) __bf16   bf16x8;
typedef __attribute__((ext_vector_type(4))) float    f32x4;
typedef __attribute__((ext_vector_type(8))) uint16_t u16x8;

__device__ inline uint16_t f2bf(float f) {          // RNE f32 -> bf16
    uint32_t u = __builtin_bit_cast(uint32_t, f);
    u += 0x7FFF + ((u >> 16) & 1);
    return (uint16_t)(u >> 16);
}
__device__ inline float bf2f(uint16_t u) {
    return __builtin_bit_cast(float, (uint32_t)u << 16);
}

// ---------------------------------------------------------------------------
// convA: xc (sink|x rows) -> bf16 [M_PAD][512], zero pad rows >= M_TOT.
// ---------------------------------------------------------------------------
__global__ __launch_bounds__(256) void convA(
    const float* __restrict__ x, const float* __restrict__ sink,
    uint16_t* __restrict__ Abf)
{
    size_t id = (size_t)blockIdx.x * 256 + threadIdx.x;   // one 8-elem chunk
    size_t e0 = id * 8;
    int row = (int)(e0 >> 9);
    int col = (int)(e0 & 511);
    u16x8 o;
    if (row < M_TOT) {
        int b = row / T_;
        int t = row - b * T_;
        const float* src = (t < NS_)
            ? &sink[((size_t)b * NS_ + t) * DM_ + col]
            : &x[((size_t)b * S_ + (t - NS_)) * DM_ + col];
        float4 v0 = *(const float4*)src;
        float4 v1 = *(const float4*)(src + 4);
        o[0] = f2bf(v0.x); o[1] = f2bf(v0.y); o[2] = f2bf(v0.z); o[3] = f2bf(v0.w);
        o[4] = f2bf(v1.x); o[5] = f2bf(v1.y); o[6] = f2bf(v1.z); o[7] = f2bf(v1.w);
    } else {
        o = (u16x8)0;
    }
    *(u16x8*)&Abf[e0] = o;
}

// ---------------------------------------------------------------------------
// convB: Bt[n][k] = W(n)[k][n%512] in bf16  (transpose + convert via LDS tile)
// ---------------------------------------------------------------------------
__global__ __launch_bounds__(256) void convB(
    const float* __restrict__ Wq, const float* __restrict__ Wk,
    const float* __restrict__ Wv, uint16_t* __restrict__ Bt)
{
    __shared__ float tile[32][65];
    const int n0 = blockIdx.x * 64, k0 = blockIdx.y * 32;
    const float* Wsrc = (n0 < 512) ? Wq : ((n0 < 1024) ? Wk : Wv);
    const int nb = n0 & 511;
    const int tid = threadIdx.x;
    const int nn = tid & 63, kk = tid >> 6;          // kk 0..3
    #pragma unroll
    for (int i = 0; i < 8; ++i)
        tile[kk + i * 4][nn] = Wsrc[(size_t)(k0 + kk + i * 4) * DOUT_ + nb + nn];
    __syncthreads();
    const int nn2 = tid >> 2, k8 = (tid & 3) * 8;
    u16x8 o;
    #pragma unroll
    for (int j = 0; j < 8; ++j) o[j] = f2bf(tile[k8 + j][nn2]);
    *(u16x8*)&Bt[(size_t)(n0 + nn2) * DM_ + k0 + k8] = o;
}

// ---------------------------------------------------------------------------
// gemm_bf16: y[M][N3](bf16) = Abf[M][512] * Bt[N3][512]^T (+bk on k third)
// 128x128 tile, BK=32, 4 waves (2x2), 16x16x32 MFMA, global_load_lds w=16
// for BOTH operands (round-4 proven structure); bf16 epilogue store.
// ---------------------------------------------------------------------------
__global__ __launch_bounds__(256) void gemm_bf16(
    const uint16_t* __restrict__ Abf, const uint16_t* __restrict__ Bt,
    const float* __restrict__ bk, uint16_t* __restrict__ y)
{
    __shared__ __align__(16) uint16_t As[128 * 32];
    __shared__ __align__(16) uint16_t Bs[128 * 32];
    const int tid  = threadIdx.x;
    const int wave = tid >> 6, lane = tid & 63;
    const int row0 = blockIdx.y * 128, col0 = blockIdx.x * 128;
    const int wm = wave >> 1, wn = wave & 1;         // 2x2 wave grid
    f32x4 acc[4][4] = {};

    const int srow  = tid >> 2;                      // staging row 0..63
    const int sslot = tid & 3;                       // 16B slot in row

    for (int k0 = 0; k0 < DM_; k0 += 32) {
        #pragma unroll
        for (int i = 0; i < 2; ++i) {
            const int r  = i * 64 + srow;
            const int ls = sslot ^ ((r >> 1) & 3);   // inverse swizzle on src
            const uint16_t* ga = Abf + (size_t)(row0 + r) * DM_ + k0 + ls * 8;
            const uint16_t* gb = Bt  + (size_t)(col0 + r) * DM_ + k0 + ls * 8;
            __builtin_amdgcn_global_load_lds(
                (const __attribute__((address_space(1))) void*)ga,
                (__attribute__((address_space(3))) void*)(As + i * 2048 + wave * 512),
                16, 0, 0);
            __builtin_amdgcn_global_load_lds(
                (const __attribute__((address_space(1))) void*)gb,
                (__attribute__((address_space(3))) void*)(Bs + i * 2048 + wave * 512),
                16, 0, 0);
        }
        __syncthreads();

        const int kslot = lane >> 4;                 // which 8-wide k slice
        const int fr    = lane & 15;
        bf16x8 af[4], bfr[4];
        #pragma unroll
        for (int mi = 0; mi < 4; ++mi) {
            const int r  = wm * 64 + mi * 16 + fr;
            const int ss = kslot ^ ((r >> 1) & 3);
            af[mi] = *(const bf16x8*)&As[r * 32 + ss * 8];
        }
        #pragma unroll
        for (int ni = 0; ni < 4; ++ni) {
            const int r  = wn * 64 + ni * 16 + fr;
            const int ss = kslot ^ ((r >> 1) & 3);
            bfr[ni] = *(const bf16x8*)&Bs[r * 32 + ss * 8];
        }
        #pragma unroll
        for (int mi = 0; mi < 4; ++mi)
            #pragma unroll
            for (int ni = 0; ni < 4; ++ni)
                acc[mi][ni] = __builtin_amdgcn_mfma_f32_16x16x32_bf16(
                    af[mi], bfr[ni], acc[mi][ni], 0, 0, 0);
        __syncthreads();
    }

    // epilogue: C row = (lane>>4)*4 + reg, col = lane&15; store bf16
    const int fr = lane & 15, fq = lane >> 4;
    #pragma unroll
    for (int ni = 0; ni < 4; ++ni) {
        const int col = col0 + wn * 64 + ni * 16 + fr;
        const float bias = (col >= 512 && col < 1024) ? bk[col - 512] : 0.f;
        #pragma unroll
        for (int mi = 0; mi < 4; ++mi) {
            #pragma unroll
            for (int r4 = 0; r4 < 4; ++r4) {
                const int row = row0 + wm * 64 + mi * 16 + fq * 4 + r4;
                if (row < M_TOT)
                    y[(size_t)row * N3 + col] = f2bf(acc[mi][ni][r4] + bias);
            }
        }
    }
}

// ---------------------------------------------------------------------------
// attn: sliding-window over bf16 y. Thread = (b, c), strip of SCHUNK s.
// Ring of 8 q/v in registers: 3 new bf16 loads per s.
// ---------------------------------------------------------------------------
__global__ __launch_bounds__(512) void attn_kernel(
    const uint16_t* __restrict__ y, const float* __restrict__ pos,
    float* __restrict__ out)
{
    __shared__ float spos[DH_ * (NS_ + W_)];
    for (int i = threadIdx.x; i < DH_ * (NS_ + W_); i += 512) spos[i] = pos[i];
    __syncthreads();

    const int c  = threadIdx.x;                 // channel 0..511
    const int b  = blockIdx.y;
    const int s0 = blockIdx.x * SCHUNK;
    const uint16_t* yb = y + (size_t)b * T_ * N3;
    const int dh = c & (DH_ - 1);

    float pp[NS_ + W_];
    #pragma unroll
    for (int p = 0; p < NS_ + W_; ++p) pp[p] = spos[dh * (NS_ + W_) + p];

    const float sq0 = bf2f(yb[0 * N3 + c]),        sq1 = bf2f(yb[1 * N3 + c]);
    const float sv0 = bf2f(yb[0 * N3 + 1024 + c]), sv1 = bf2f(yb[1 * N3 + 1024 + c]);

    float qr[W_], vr[W_];
    #pragma unroll
    for (int j = 0; j < W_ - 1; ++j) {
        const uint16_t* rq = yb + (size_t)(NS_ + s0 + j) * N3 + c;
        qr[j] = bf2f(rq[0]);
        vr[j] = bf2f(rq[1024]);
    }

    for (int i = 0; i < SCHUNK; ++i) {
        const int s = s0 + i;
        int tq = NS_ + s + (W_ - 1);
        if (tq > T_ - 1) tq = T_ - 1;            // clamp (masked below)
        const uint16_t* rq = yb + (size_t)tq * N3 + c;
        qr[W_ - 1] = bf2f(rq[0]);
        vr[W_ - 1] = bf2f(rq[1024]);
        const float kv = bf2f(yb[(size_t)(NS_ + s) * N3 + 512 + c]);

        float sc[NS_ + W_];
        sc[0] = (sq0 + pp[0]) * kv;
        sc[1] = (sq1 + pp[1]) * kv;
        #pragma unroll
        for (int r = 0; r < W_; ++r) sc[NS_ + r] = (qr[r] + pp[NS_ + r]) * kv;
        if (s > S_ - W_) {                       // tail masking (uniform)
            const int nv = S_ - s;
            #pragma unroll
            for (int r = 0; r < W_; ++r)
                if (r >= nv) sc[NS_ + r] = -INFINITY;
        }

        float m = sc[0];
        #pragma unroll
        for (int p = 1; p < NS_ + W_; ++p) m = fmaxf(m, sc[p]);
        float e[NS_ + W_], sum = 0.f;
        #pragma unroll
        for (int p = 0; p < NS_ + W_; ++p) { e[p] = __expf(sc[p] - m); sum += e[p]; }
        float accv = e[0] * sv0 + e[1] * sv1;
        #pragma unroll
        for (int r = 0; r < W_; ++r) accv = fmaf(e[NS_ + r], vr[r], accv);

        out[((size_t)b * S_ + s) * DOUT_ + c] = accv / sum;

        #pragma unroll
        for (int j = 0; j < W_ - 1; ++j) { qr[j] = qr[j + 1]; vr[j] = vr[j + 1]; }
    }
}

// ---------------------------------------------------------------------------
extern "C" void kernel_launch(void* const* d_in, const int* in_sizes, int n_in,
                              void* d_out, int out_size, void* d_ws, size_t ws_size,
                              hipStream_t stream) {
    const float* x    = (const float*)d_in[0];
    const float* sink = (const float*)d_in[1];
    const float* Wk   = (const float*)d_in[2];
    const float* bk   = (const float*)d_in[3];
    const float* Wq   = (const float*)d_in[4];
    const float* Wv   = (const float*)d_in[5];
    const float* pos  = (const float*)d_in[6];

    char* ws = (char*)d_ws;
    uint16_t* y   = (uint16_t*)ws;                                // 25,190,400 B
    uint16_t* Abf = (uint16_t*)(ws + (size_t)M_TOT * N3 * 2);     //  8,519,680 B
    uint16_t* Bt  = (uint16_t*)(ws + (size_t)M_TOT * N3 * 2
                                   + (size_t)M_PAD * DM_ * 2);    //  1,572,864 B

    convA<<<dim3(M_PAD * DM_ / 8 / 256), 256, 0, stream>>>(x, sink, Abf);
    convB<<<dim3(N3 / 64, DM_ / 32), 256, 0, stream>>>(Wq, Wk, Wv, Bt);
    gemm_bf16<<<dim3(N3 / 128, M_PAD / 128), 256, 0, stream>>>(Abf, Bt, bk, y);
    attn_kernel<<<dim3(S_ / SCHUNK, B_), 512, 0, stream>>>(y, pos, (float*)d_out);
}

// Round 8
// 60.581 us; speedup vs baseline: 1.3060x; 1.1256x over previous
//
#include <hip/hip_runtime.h>
#include <hip/hip_bf16.h>
#include <math.h>
#include <stdint.h>

#define B_ 4
#define S_ 2048
#define DM_ 512
#define H_ 8
#define DH_ 64
#define DOUT_ 512
#define W_ 8
#define NS_ 2
#define T_ (NS_ + S_)      // 2050 rows per batch in xc
#define M_TOT (B_ * T_)    // 8200
#define M_PAD 8320         // 65 * 128, zero-padded tail
#define N3 1536            // q | k | v concatenated columns
#define SCHUNK 16          // s-strip per thread in attn

typedef __attribute__((ext_vector_type(8))) __bf16   bf16x8;
typedef __attribute__((ext_vector_type(4))) float    f32x4;
typedef __attribute__((ext_vector_type(8))) uint16_t u16x8;

__device__ inline uint16_t f2bf(float f) {          // RNE f32 -> bf16
    uint32_t u = __builtin_bit_cast(uint32_t, f);
    u += 0x7FFF + ((u >> 16) & 1);
    return (uint16_t)(u >> 16);
}
__device__ inline float bf2f(uint16_t u) {
    return __builtin_bit_cast(float, (uint32_t)u << 16);
}

// ---------------------------------------------------------------------------
// convA: xc (sink|x rows) -> bf16 [M_PAD][512], zero pad rows >= M_TOT.
// ---------------------------------------------------------------------------
__global__ __launch_bounds__(256) void convA(
    const float* __restrict__ x, const float* __restrict__ sink,
    uint16_t* __restrict__ Abf)
{
    size_t id = (size_t)blockIdx.x * 256 + threadIdx.x;   // one 8-elem chunk
    size_t e0 = id * 8;
    int row = (int)(e0 >> 9);
    int col = (int)(e0 & 511);
    u16x8 o;
    if (row < M_TOT) {
        int b = row / T_;
        int t = row - b * T_;
        const float* src = (t < NS_)
            ? &sink[((size_t)b * NS_ + t) * DM_ + col]
            : &x[((size_t)b * S_ + (t - NS_)) * DM_ + col];
        float4 v0 = *(const float4*)src;
        float4 v1 = *(const float4*)(src + 4);
        o[0] = f2bf(v0.x); o[1] = f2bf(v0.y); o[2] = f2bf(v0.z); o[3] = f2bf(v0.w);
        o[4] = f2bf(v1.x); o[5] = f2bf(v1.y); o[6] = f2bf(v1.z); o[7] = f2bf(v1.w);
    } else {
        o = (u16x8)0;
    }
    *(u16x8*)&Abf[e0] = o;
}

// ---------------------------------------------------------------------------
// convB: Bt[n][k] = W(n)[k][n%512] in bf16  (transpose + convert via LDS tile)
// ---------------------------------------------------------------------------
__global__ __launch_bounds__(256) void convB(
    const float* __restrict__ Wq, const float* __restrict__ Wk,
    const float* __restrict__ Wv, uint16_t* __restrict__ Bt)
{
    __shared__ float tile[32][65];
    const int n0 = blockIdx.x * 64, k0 = blockIdx.y * 32;
    const float* Wsrc = (n0 < 512) ? Wq : ((n0 < 1024) ? Wk : Wv);
    const int nb = n0 & 511;
    const int tid = threadIdx.x;
    const int nn = tid & 63, kk = tid >> 6;          // kk 0..3
    #pragma unroll
    for (int i = 0; i < 8; ++i)
        tile[kk + i * 4][nn] = Wsrc[(size_t)(k0 + kk + i * 4) * DOUT_ + nb + nn];
    __syncthreads();
    const int nn2 = tid >> 2, k8 = (tid & 3) * 8;
    u16x8 o;
    #pragma unroll
    for (int j = 0; j < 8; ++j) o[j] = f2bf(tile[k8 + j][nn2]);
    *(u16x8*)&Bt[(size_t)(n0 + nn2) * DM_ + k0 + k8] = o;
}

// ---------------------------------------------------------------------------
// gemm_bf16: y[M][N3](bf16) = Abf[M][512] * Bt[N3][512]^T (+bk on k third)
// 128x128 tile, BK=32, 4 waves (2x2), 16x16x32 MFMA, global_load_lds w=16.
// Epilogue: per-wave LDS transpose (stride 72) -> coalesced u16x8 stores.
// ---------------------------------------------------------------------------
__global__ __launch_bounds__(256) void gemm_bf16(
    const uint16_t* __restrict__ Abf, const uint16_t* __restrict__ Bt,
    const float* __restrict__ bk, uint16_t* __restrict__ y)
{
    __shared__ __align__(16) uint16_t As[128 * 32];
    __shared__ __align__(16) uint16_t Bs[128 * 32];
    __shared__ __align__(16) uint16_t Ep[4][16 * 72];   // per-wave epilogue
    const int tid  = threadIdx.x;
    const int wave = tid >> 6, lane = tid & 63;
    const int row0 = blockIdx.y * 128, col0 = blockIdx.x * 128;
    const int wm = wave >> 1, wn = wave & 1;         // 2x2 wave grid
    f32x4 acc[4][4] = {};

    const int srow  = tid >> 2;                      // staging row 0..63
    const int sslot = tid & 3;                       // 16B slot in row

    for (int k0 = 0; k0 < DM_; k0 += 32) {
        #pragma unroll
        for (int i = 0; i < 2; ++i) {
            const int r  = i * 64 + srow;
            const int ls = sslot ^ ((r >> 1) & 3);   // inverse swizzle on src
            const uint16_t* ga = Abf + (size_t)(row0 + r) * DM_ + k0 + ls * 8;
            const uint16_t* gb = Bt  + (size_t)(col0 + r) * DM_ + k0 + ls * 8;
            __builtin_amdgcn_global_load_lds(
                (const __attribute__((address_space(1))) void*)ga,
                (__attribute__((address_space(3))) void*)(As + i * 2048 + wave * 512),
                16, 0, 0);
            __builtin_amdgcn_global_load_lds(
                (const __attribute__((address_space(1))) void*)gb,
                (__attribute__((address_space(3))) void*)(Bs + i * 2048 + wave * 512),
                16, 0, 0);
        }
        __syncthreads();

        const int kslot = lane >> 4;                 // which 8-wide k slice
        const int fr    = lane & 15;
        bf16x8 af[4], bfr[4];
        #pragma unroll
        for (int mi = 0; mi < 4; ++mi) {
            const int r  = wm * 64 + mi * 16 + fr;
            const int ss = kslot ^ ((r >> 1) & 3);
            af[mi] = *(const bf16x8*)&As[r * 32 + ss * 8];
        }
        #pragma unroll
        for (int ni = 0; ni < 4; ++ni) {
            const int r  = wn * 64 + ni * 16 + fr;
            const int ss = kslot ^ ((r >> 1) & 3);
            bfr[ni] = *(const bf16x8*)&Bs[r * 32 + ss * 8];
        }
        #pragma unroll
        for (int mi = 0; mi < 4; ++mi)
            #pragma unroll
            for (int ni = 0; ni < 4; ++ni)
                acc[mi][ni] = __builtin_amdgcn_mfma_f32_16x16x32_bf16(
                    af[mi], bfr[ni], acc[mi][ni], 0, 0, 0);
        __syncthreads();
    }

    // ---- epilogue: wave-private LDS transpose, coalesced 16B stores ----
    const int fr = lane & 15, fq = lane >> 4;
    float bias[4];
    #pragma unroll
    for (int ni = 0; ni < 4; ++ni) {
        const int col = col0 + wn * 64 + ni * 16 + fr;
        bias[ni] = (col >= 512 && col < 1024) ? bk[col - 512] : 0.f;
    }
    const int rrow = lane >> 3;                      // 0..7   (read row)
    const int rcol = (lane & 7) * 8;                 // 0..56  (read col, 8 el)
    uint16_t* ep = Ep[wave];
    #pragma unroll
    for (int mi = 0; mi < 4; ++mi) {
        // scatter 16x64 chunk into LDS (row_l = fq*4+r4, col_l = ni*16+fr)
        #pragma unroll
        for (int ni = 0; ni < 4; ++ni)
            #pragma unroll
            for (int r4 = 0; r4 < 4; ++r4)
                ep[(fq * 4 + r4) * 72 + ni * 16 + fr] =
                    f2bf(acc[mi][ni][r4] + bias[ni]);
        __builtin_amdgcn_s_waitcnt(0);               // lgkmcnt(0) wave-local
        #pragma unroll
        for (int it = 0; it < 2; ++it) {
            const int rl  = it * 8 + rrow;
            const int row = row0 + wm * 64 + mi * 16 + rl;
            u16x8 v = *(const u16x8*)&ep[rl * 72 + rcol];
            if (row < M_TOT)
                *(u16x8*)&y[(size_t)row * N3 + col0 + wn * 64 + rcol] = v;
        }
        __builtin_amdgcn_s_waitcnt(0);               // drain reads before reuse
    }
}

// ---------------------------------------------------------------------------
// attn: sliding-window over bf16 y. Thread = (b, c), strip of SCHUNK s.
// Ring of 8 q/v in registers: 3 new bf16 loads per s.
// ---------------------------------------------------------------------------
__global__ __launch_bounds__(512) void attn_kernel(
    const uint16_t* __restrict__ y, const float* __restrict__ pos,
    float* __restrict__ out)
{
    __shared__ float spos[DH_ * (NS_ + W_)];
    for (int i = threadIdx.x; i < DH_ * (NS_ + W_); i += 512) spos[i] = pos[i];
    __syncthreads();

    const int c  = threadIdx.x;                 // channel 0..511
    const int b  = blockIdx.y;
    const int s0 = blockIdx.x * SCHUNK;
    const uint16_t* yb = y + (size_t)b * T_ * N3;
    const int dh = c & (DH_ - 1);

    float pp[NS_ + W_];
    #pragma unroll
    for (int p = 0; p < NS_ + W_; ++p) pp[p] = spos[dh * (NS_ + W_) + p];

    const float sq0 = bf2f(yb[0 * N3 + c]),        sq1 = bf2f(yb[1 * N3 + c]);
    const float sv0 = bf2f(yb[0 * N3 + 1024 + c]), sv1 = bf2f(yb[1 * N3 + 1024 + c]);

    float qr[W_], vr[W_];
    #pragma unroll
    for (int j = 0; j < W_ - 1; ++j) {
        const uint16_t* rq = yb + (size_t)(NS_ + s0 + j) * N3 + c;
        qr[j] = bf2f(rq[0]);
        vr[j] = bf2f(rq[1024]);
    }

    for (int i = 0; i < SCHUNK; ++i) {
        const int s = s0 + i;
        int tq = NS_ + s + (W_ - 1);
        if (tq > T_ - 1) tq = T_ - 1;            // clamp (masked below)
        const uint16_t* rq = yb + (size_t)tq * N3 + c;
        qr[W_ - 1] = bf2f(rq[0]);
        vr[W_ - 1] = bf2f(rq[1024]);
        const float kv = bf2f(yb[(size_t)(NS_ + s) * N3 + 512 + c]);

        float sc[NS_ + W_];
        sc[0] = (sq0 + pp[0]) * kv;
        sc[1] = (sq1 + pp[1]) * kv;
        #pragma unroll
        for (int r = 0; r < W_; ++r) sc[NS_ + r] = (qr[r] + pp[NS_ + r]) * kv;
        if (s > S_ - W_) {                       // tail masking (uniform)
            const int nv = S_ - s;
            #pragma unroll
            for (int r = 0; r < W_; ++r)
                if (r >= nv) sc[NS_ + r] = -INFINITY;
        }

        float m = sc[0];
        #pragma unroll
        for (int p = 1; p < NS_ + W_; ++p) m = fmaxf(m, sc[p]);
        float e[NS_ + W_], sum = 0.f;
        #pragma unroll
        for (int p = 0; p < NS_ + W_; ++p) { e[p] = __expf(sc[p] - m); sum += e[p]; }
        float accv = e[0] * sv0 + e[1] * sv1;
        #pragma unroll
        for (int r = 0; r < W_; ++r) accv = fmaf(e[NS_ + r], vr[r], accv);

        out[((size_t)b * S_ + s) * DOUT_ + c] = accv / sum;

        #pragma unroll
        for (int j = 0; j < W_ - 1; ++j) { qr[j] = qr[j + 1]; vr[j] = vr[j + 1]; }
    }
}

// ---------------------------------------------------------------------------
extern "C" void kernel_launch(void* const* d_in, const int* in_sizes, int n_in,
                              void* d_out, int out_size, void* d_ws, size_t ws_size,
                              hipStream_t stream) {
    const float* x    = (const float*)d_in[0];
    const float* sink = (const float*)d_in[1];
    const float* Wk   = (const float*)d_in[2];
    const float* bk   = (const float*)d_in[3];
    const float* Wq   = (const float*)d_in[4];
    const float* Wv   = (const float*)d_in[5];
    const float* pos  = (const float*)d_in[6];

    char* ws = (char*)d_ws;
    uint16_t* y   = (uint16_t*)ws;                                // 25,190,400 B
    uint16_t* Abf = (uint16_t*)(ws + (size_t)M_TOT * N3 * 2);     //  8,519,680 B
    uint16_t* Bt  = (uint16_t*)(ws + (size_t)M_TOT * N3 * 2
                                   + (size_t)M_PAD * DM_ * 2);    //  1,572,864 B

    convA<<<dim3(M_PAD * DM_ / 8 / 256), 256, 0, stream>>>(x, sink, Abf);
    convB<<<dim3(N3 / 64, DM_ / 32), 256, 0, stream>>>(Wq, Wk, Wv, Bt);
    gemm_bf16<<<dim3(N3 / 128, M_PAD / 128), 256, 0, stream>>>(Abf, Bt, bk, y);
    attn_kernel<<<dim3(S_ / SCHUNK, B_), 512, 0, stream>>>(y, pos, (float*)d_out);
}

// Round 9
// 56.960 us; speedup vs baseline: 1.3891x; 1.0636x over previous
//
#include <hip/hip_runtime.h>
#include <hip/hip_bf16.h>
#include <math.h>
#include <stdint.h>

#define B_ 4
#define S_ 2048
#define DM_ 512
#define H_ 8
#define DH_ 64
#define DOUT_ 512
#define W_ 8
#define NS_ 2
#define T_ (NS_ + S_)      // 2050 rows per batch in xc
#define M_TOT (B_ * T_)    // 8200
#define M_PAD 8320         // 65 * 128, zero-padded tail
#define N3 1536            // q | k | v concatenated columns
#define SCHUNK 16          // s-strip per thread in attn
#define NBLK_A 2080        // convA blocks in merged conv kernel

typedef __attribute__((ext_vector_type(8))) __bf16   bf16x8;
typedef __attribute__((ext_vector_type(4))) float    f32x4;
typedef __attribute__((ext_vector_type(8))) uint16_t u16x8;

__device__ inline uint16_t f2bf(float f) {          // RNE f32 -> bf16
    uint32_t u = __builtin_bit_cast(uint32_t, f);
    u += 0x7FFF + ((u >> 16) & 1);
    return (uint16_t)(u >> 16);
}
__device__ inline float bf2f(uint16_t u) {
    return __builtin_bit_cast(float, (uint32_t)u << 16);
}

// ---------------------------------------------------------------------------
// conv_fused: blocks [0, NBLK_A) do convA (xc -> bf16 Abf, zero-padded);
// blocks [NBLK_A, ...) do convB (W transpose+convert -> Bt).
// ---------------------------------------------------------------------------
__global__ __launch_bounds__(256) void conv_fused(
    const float* __restrict__ x, const float* __restrict__ sink,
    const float* __restrict__ Wq, const float* __restrict__ Wk,
    const float* __restrict__ Wv,
    uint16_t* __restrict__ Abf, uint16_t* __restrict__ Bt)
{
    __shared__ float tile[32][65];
    if (blockIdx.x < NBLK_A) {
        size_t id = (size_t)blockIdx.x * 256 + threadIdx.x;   // one 8-elem chunk
        size_t e0 = id * 8;
        int row = (int)(e0 >> 9);
        int col = (int)(e0 & 511);
        u16x8 o;
        if (row < M_TOT) {
            int b = row / T_;
            int t = row - b * T_;
            const float* src = (t < NS_)
                ? &sink[((size_t)b * NS_ + t) * DM_ + col]
                : &x[((size_t)b * S_ + (t - NS_)) * DM_ + col];
            float4 v0 = *(const float4*)src;
            float4 v1 = *(const float4*)(src + 4);
            o[0] = f2bf(v0.x); o[1] = f2bf(v0.y); o[2] = f2bf(v0.z); o[3] = f2bf(v0.w);
            o[4] = f2bf(v1.x); o[5] = f2bf(v1.y); o[6] = f2bf(v1.z); o[7] = f2bf(v1.w);
        } else {
            o = (u16x8)0;
        }
        *(u16x8*)&Abf[e0] = o;
    } else {
        const int bx = blockIdx.x - NBLK_A;           // 0..383
        const int n0 = (bx % 24) * 64, k0 = (bx / 24) * 32;
        const float* Wsrc = (n0 < 512) ? Wq : ((n0 < 1024) ? Wk : Wv);
        const int nb = n0 & 511;
        const int tid = threadIdx.x;
        const int nn = tid & 63, kk = tid >> 6;       // kk 0..3
        #pragma unroll
        for (int i = 0; i < 8; ++i)
            tile[kk + i * 4][nn] = Wsrc[(size_t)(k0 + kk + i * 4) * DOUT_ + nb + nn];
        __syncthreads();
        const int nn2 = tid >> 2, k8 = (tid & 3) * 8;
        u16x8 o;
        #pragma unroll
        for (int j = 0; j < 8; ++j) o[j] = f2bf(tile[k8 + j][nn2]);
        *(u16x8*)&Bt[(size_t)(n0 + nn2) * DM_ + k0 + k8] = o;
    }
}

// ---------------------------------------------------------------------------
// gemm_bf16: y[M][N3](bf16) = Abf[M][512] * Bt[N3][512]^T (+bk on k third)
// 128x128 tile, BK=32, 4 waves (2x2), 16x16x32 MFMA.
// Issue-early double-buffered staging: STAGE(k+1) before compute(k);
// counted vmcnt(4) + raw s_barrier keeps next-tile loads in flight.
// Epilogue: per-wave LDS transpose (stride 72) -> coalesced u16x8 stores.
// ---------------------------------------------------------------------------
__global__ __launch_bounds__(256) void gemm_bf16(
    const uint16_t* __restrict__ Abf, const uint16_t* __restrict__ Bt,
    const float* __restrict__ bk, uint16_t* __restrict__ y)
{
    __shared__ __align__(16) uint16_t As[2][128 * 32];
    __shared__ __align__(16) uint16_t Bs[2][128 * 32];
    __shared__ __align__(16) uint16_t Ep[4][16 * 72];   // per-wave epilogue
    const int tid  = threadIdx.x;
    const int wave = tid >> 6, lane = tid & 63;
    const int row0 = blockIdx.y * 128, col0 = blockIdx.x * 128;
    const int wm = wave >> 1, wn = wave & 1;         // 2x2 wave grid
    f32x4 acc[4][4] = {};

    const int srow  = tid >> 2;                      // staging row 0..63
    const int sslot = tid & 3;                       // 16B slot in row

    // issue the 4 global_load_lds for K-step ks into buffer d
    auto STAGE = [&](int ks, int d) {
        const int k0 = ks * 32;
        #pragma unroll
        for (int i = 0; i < 2; ++i) {
            const int r  = i * 64 + srow;
            const int ls = sslot ^ ((r >> 1) & 3);   // inverse swizzle on src
            const uint16_t* ga = Abf + (size_t)(row0 + r) * DM_ + k0 + ls * 8;
            const uint16_t* gb = Bt  + (size_t)(col0 + r) * DM_ + k0 + ls * 8;
            __builtin_amdgcn_global_load_lds(
                (const __attribute__((address_space(1))) void*)ga,
                (__attribute__((address_space(3))) void*)(&As[d][0] + i * 2048 + wave * 512),
                16, 0, 0);
            __builtin_amdgcn_global_load_lds(
                (const __attribute__((address_space(1))) void*)gb,
                (__attribute__((address_space(3))) void*)(&Bs[d][0] + i * 2048 + wave * 512),
                16, 0, 0);
        }
    };

    const int kslot = lane >> 4;                     // which 8-wide k slice
    const int fr    = lane & 15;

    auto COMPUTE = [&](int cur) {
        bf16x8 af[4], bfr[4];
        #pragma unroll
        for (int mi = 0; mi < 4; ++mi) {
            const int r  = wm * 64 + mi * 16 + fr;
            const int ss = kslot ^ ((r >> 1) & 3);
            af[mi] = *(const bf16x8*)&As[cur][r * 32 + ss * 8];
        }
        #pragma unroll
        for (int ni = 0; ni < 4; ++ni) {
            const int r  = wn * 64 + ni * 16 + fr;
            const int ss = kslot ^ ((r >> 1) & 3);
            bfr[ni] = *(const bf16x8*)&Bs[cur][r * 32 + ss * 8];
        }
        #pragma unroll
        for (int mi = 0; mi < 4; ++mi)
            #pragma unroll
            for (int ni = 0; ni < 4; ++ni)
                acc[mi][ni] = __builtin_amdgcn_mfma_f32_16x16x32_bf16(
                    af[mi], bfr[ni], acc[mi][ni], 0, 0, 0);
    };

    STAGE(0, 0);
    for (int ks = 0; ks < 15; ++ks) {
        const int cur = ks & 1;
        STAGE(ks + 1, cur ^ 1);
        asm volatile("s_waitcnt vmcnt(4)" ::: "memory");  // stage(ks) landed
        __builtin_amdgcn_s_barrier();
        __builtin_amdgcn_sched_barrier(0);
        COMPUTE(cur);
        __builtin_amdgcn_sched_barrier(0);
        __builtin_amdgcn_s_barrier();
    }
    {   // last K-step: nothing left to stage
        asm volatile("s_waitcnt vmcnt(0)" ::: "memory");
        __builtin_amdgcn_s_barrier();
        __builtin_amdgcn_sched_barrier(0);
        COMPUTE(1);                                   // ks=15 -> buf 1
        __builtin_amdgcn_sched_barrier(0);
        __builtin_amdgcn_s_barrier();
    }

    // ---- epilogue: wave-private LDS transpose, coalesced 16B stores ----
    const int fq = lane >> 4;
    float bias[4];
    #pragma unroll
    for (int ni = 0; ni < 4; ++ni) {
        const int col = col0 + wn * 64 + ni * 16 + fr;
        bias[ni] = (col >= 512 && col < 1024) ? bk[col - 512] : 0.f;
    }
    const int rrow = lane >> 3;                      // 0..7   (read row)
    const int rcol = (lane & 7) * 8;                 // 0..56  (read col, 8 el)
    uint16_t* ep = Ep[wave];
    #pragma unroll
    for (int mi = 0; mi < 4; ++mi) {
        #pragma unroll
        for (int ni = 0; ni < 4; ++ni)
            #pragma unroll
            for (int r4 = 0; r4 < 4; ++r4)
                ep[(fq * 4 + r4) * 72 + ni * 16 + fr] =
                    f2bf(acc[mi][ni][r4] + bias[ni]);
        __builtin_amdgcn_s_waitcnt(0);               // wave-local LDS drain
        #pragma unroll
        for (int it = 0; it < 2; ++it) {
            const int rl  = it * 8 + rrow;
            const int row = row0 + wm * 64 + mi * 16 + rl;
            u16x8 v = *(const u16x8*)&ep[rl * 72 + rcol];
            if (row < M_TOT)
                *(u16x8*)&y[(size_t)row * N3 + col0 + wn * 64 + rcol] = v;
        }
        __builtin_amdgcn_s_waitcnt(0);               // drain reads before reuse
    }
}

// ---------------------------------------------------------------------------
// attn: sliding-window over bf16 y. Thread = (b, c), strip of SCHUNK s.
// Ring of 8 q/v in registers: 3 new bf16 loads per s.
// ---------------------------------------------------------------------------
__global__ __launch_bounds__(512) void attn_kernel(
    const uint16_t* __restrict__ y, const float* __restrict__ pos,
    float* __restrict__ out)
{
    __shared__ float spos[DH_ * (NS_ + W_)];
    for (int i = threadIdx.x; i < DH_ * (NS_ + W_); i += 512) spos[i] = pos[i];
    __syncthreads();

    const int c  = threadIdx.x;                 // channel 0..511
    const int b  = blockIdx.y;
    const int s0 = blockIdx.x * SCHUNK;
    const uint16_t* yb = y + (size_t)b * T_ * N3;
    const int dh = c & (DH_ - 1);

    float pp[NS_ + W_];
    #pragma unroll
    for (int p = 0; p < NS_ + W_; ++p) pp[p] = spos[dh * (NS_ + W_) + p];

    const float sq0 = bf2f(yb[0 * N3 + c]),        sq1 = bf2f(yb[1 * N3 + c]);
    const float sv0 = bf2f(yb[0 * N3 + 1024 + c]), sv1 = bf2f(yb[1 * N3 + 1024 + c]);

    float qr[W_], vr[W_];
    #pragma unroll
    for (int j = 0; j < W_ - 1; ++j) {
        const uint16_t* rq = yb + (size_t)(NS_ + s0 + j) * N3 + c;
        qr[j] = bf2f(rq[0]);
        vr[j] = bf2f(rq[1024]);
    }

    for (int i = 0; i < SCHUNK; ++i) {
        const int s = s0 + i;
        int tq = NS_ + s + (W_ - 1);
        if (tq > T_ - 1) tq = T_ - 1;            // clamp (masked below)
        const uint16_t* rq = yb + (size_t)tq * N3 + c;
        qr[W_ - 1] = bf2f(rq[0]);
        vr[W_ - 1] = bf2f(rq[1024]);
        const float kv = bf2f(yb[(size_t)(NS_ + s) * N3 + 512 + c]);

        float sc[NS_ + W_];
        sc[0] = (sq0 + pp[0]) * kv;
        sc[1] = (sq1 + pp[1]) * kv;
        #pragma unroll
        for (int r = 0; r < W_; ++r) sc[NS_ + r] = (qr[r] + pp[NS_ + r]) * kv;
        if (s > S_ - W_) {                       // tail masking (uniform)
            const int nv = S_ - s;
            #pragma unroll
            for (int r = 0; r < W_; ++r)
                if (r >= nv) sc[NS_ + r] = -INFINITY;
        }

        float m = sc[0];
        #pragma unroll
        for (int p = 1; p < NS_ + W_; ++p) m = fmaxf(m, sc[p]);
        float e[NS_ + W_], sum = 0.f;
        #pragma unroll
        for (int p = 0; p < NS_ + W_; ++p) { e[p] = __expf(sc[p] - m); sum += e[p]; }
        float accv = e[0] * sv0 + e[1] * sv1;
        #pragma unroll
        for (int r = 0; r < W_; ++r) accv = fmaf(e[NS_ + r], vr[r], accv);

        out[((size_t)b * S_ + s) * DOUT_ + c] = accv / sum;

        #pragma unroll
        for (int j = 0; j < W_ - 1; ++j) { qr[j] = qr[j + 1]; vr[j] = vr[j + 1]; }
    }
}

// ---------------------------------------------------------------------------
extern "C" void kernel_launch(void* const* d_in, const int* in_sizes, int n_in,
                              void* d_out, int out_size, void* d_ws, size_t ws_size,
                              hipStream_t stream) {
    const float* x    = (const float*)d_in[0];
    const float* sink = (const float*)d_in[1];
    const float* Wk   = (const float*)d_in[2];
    const float* bk   = (const float*)d_in[3];
    const float* Wq   = (const float*)d_in[4];
    const float* Wv   = (const float*)d_in[5];
    const float* pos  = (const float*)d_in[6];

    char* ws = (char*)d_ws;
    uint16_t* y   = (uint16_t*)ws;                                // 25,190,400 B
    uint16_t* Abf = (uint16_t*)(ws + (size_t)M_TOT * N3 * 2);     //  8,519,680 B
    uint16_t* Bt  = (uint16_t*)(ws + (size_t)M_TOT * N3 * 2
                                   + (size_t)M_PAD * DM_ * 2);    //  1,572,864 B

    conv_fused<<<dim3(NBLK_A + 384), 256, 0, stream>>>(x, sink, Wq, Wk, Wv, Abf, Bt);
    gemm_bf16<<<dim3(N3 / 128, M_PAD / 128), 256, 0, stream>>>(Abf, Bt, bk, y);
    attn_kernel<<<dim3(S_ / SCHUNK, B_), 512, 0, stream>>>(y, pos, (float*)d_out);
}

// Round 10
// 52.867 us; speedup vs baseline: 1.4966x; 1.0774x over previous
//
#include <hip/hip_runtime.h>
#include <hip/hip_bf16.h>
#include <math.h>
#include <stdint.h>

#define B_ 4
#define S_ 2048
#define DM_ 512
#define H_ 8
#define DH_ 64
#define DOUT_ 512
#define W_ 8
#define NS_ 2
#define T_ (NS_ + S_)      // 2050 rows per batch in xc
#define M_TOT (B_ * T_)    // 8200
#define M_PAD 8320         // 65 * 128, zero-padded tail
#define N3 1536            // q | k | v concatenated columns
#define SCHUNK 16          // s-strip per thread in attn
#define NBLK_A 2080        // convA blocks in merged conv kernel

typedef __attribute__((ext_vector_type(8))) __bf16   bf16x8;
typedef __attribute__((ext_vector_type(4))) float    f32x4;
typedef __attribute__((ext_vector_type(8))) uint16_t u16x8;

__device__ inline uint16_t f2bf(float f) {          // RNE f32 -> bf16
    uint32_t u = __builtin_bit_cast(uint32_t, f);
    u += 0x7FFF + ((u >> 16) & 1);
    return (uint16_t)(u >> 16);
}
__device__ inline float bf2f(uint16_t u) {
    return __builtin_bit_cast(float, (uint32_t)u << 16);
}

// ---------------------------------------------------------------------------
// conv_fused: blocks [0, NBLK_A) do convA (xc -> bf16 Abf, zero-padded);
// blocks [NBLK_A, ...) do convB (W transpose+convert -> Bt).
// ---------------------------------------------------------------------------
__global__ __launch_bounds__(256) void conv_fused(
    const float* __restrict__ x, const float* __restrict__ sink,
    const float* __restrict__ Wq, const float* __restrict__ Wk,
    const float* __restrict__ Wv,
    uint16_t* __restrict__ Abf, uint16_t* __restrict__ Bt)
{
    __shared__ float tile[32][65];
    if (blockIdx.x < NBLK_A) {
        size_t id = (size_t)blockIdx.x * 256 + threadIdx.x;   // one 8-elem chunk
        size_t e0 = id * 8;
        int row = (int)(e0 >> 9);
        int col = (int)(e0 & 511);
        u16x8 o;
        if (row < M_TOT) {
            int b = row / T_;
            int t = row - b * T_;
            const float* src = (t < NS_)
                ? &sink[((size_t)b * NS_ + t) * DM_ + col]
                : &x[((size_t)b * S_ + (t - NS_)) * DM_ + col];
            float4 v0 = *(const float4*)src;
            float4 v1 = *(const float4*)(src + 4);
            o[0] = f2bf(v0.x); o[1] = f2bf(v0.y); o[2] = f2bf(v0.z); o[3] = f2bf(v0.w);
            o[4] = f2bf(v1.x); o[5] = f2bf(v1.y); o[6] = f2bf(v1.z); o[7] = f2bf(v1.w);
        } else {
            o = (u16x8)0;
        }
        *(u16x8*)&Abf[e0] = o;
    } else {
        const int bx = blockIdx.x - NBLK_A;           // 0..383
        const int n0 = (bx % 24) * 64, k0 = (bx / 24) * 32;
        const float* Wsrc = (n0 < 512) ? Wq : ((n0 < 1024) ? Wk : Wv);
        const int nb = n0 & 511;
        const int tid = threadIdx.x;
        const int nn = tid & 63, kk = tid >> 6;       // kk 0..3
        #pragma unroll
        for (int i = 0; i < 8; ++i)
            tile[kk + i * 4][nn] = Wsrc[(size_t)(k0 + kk + i * 4) * DOUT_ + nb + nn];
        __syncthreads();
        const int nn2 = tid >> 2, k8 = (tid & 3) * 8;
        u16x8 o;
        #pragma unroll
        for (int j = 0; j < 8; ++j) o[j] = f2bf(tile[k8 + j][nn2]);
        *(u16x8*)&Bt[(size_t)(n0 + nn2) * DM_ + k0 + k8] = o;
    }
}

// ---------------------------------------------------------------------------
// gemm_bf16: y[M][N3](bf16) = Abf[M][512] * Bt[N3][512]^T (+bk on k third)
// 128x128 tile, BK=32, 4 waves (2x2), 16x16x32 MFMA.
// 3-deep staging pipeline: STAGE(ks+2) while computing ks; steady-state
// vmcnt(8) leaves 2 stages (8 loads) in flight -> 2 compute phases of
// latency cover. LDS: 3 x 16KB buffers; epilogue scratch aliased on buf 0.
// ---------------------------------------------------------------------------
__global__ __launch_bounds__(256) void gemm_bf16(
    const uint16_t* __restrict__ Abf, const uint16_t* __restrict__ Bt,
    const float* __restrict__ bk, uint16_t* __restrict__ y)
{
    __shared__ __align__(16) uint16_t lds[3 * 8192];   // 48 KB total
    const int tid  = threadIdx.x;
    const int wave = tid >> 6, lane = tid & 63;
    const int row0 = blockIdx.y * 128, col0 = blockIdx.x * 128;
    const int wm = wave >> 1, wn = wave & 1;         // 2x2 wave grid
    f32x4 acc[4][4] = {};

    const int srow  = tid >> 2;                      // staging row 0..63
    const int sslot = tid & 3;                       // 16B slot in row

    // issue the 4 global_load_lds for K-step ks into buffer d
    auto STAGE = [&](int ks, int d) {
        const int k0 = ks * 32;
        uint16_t* As = lds + d * 8192;
        uint16_t* Bs = lds + d * 8192 + 4096;
        #pragma unroll
        for (int i = 0; i < 2; ++i) {
            const int r  = i * 64 + srow;
            const int ls = sslot ^ ((r >> 1) & 3);   // inverse swizzle on src
            const uint16_t* ga = Abf + (size_t)(row0 + r) * DM_ + k0 + ls * 8;
            const uint16_t* gb = Bt  + (size_t)(col0 + r) * DM_ + k0 + ls * 8;
            __builtin_amdgcn_global_load_lds(
                (const __attribute__((address_space(1))) void*)ga,
                (__attribute__((address_space(3))) void*)(As + i * 2048 + wave * 512),
                16, 0, 0);
            __builtin_amdgcn_global_load_lds(
                (const __attribute__((address_space(1))) void*)gb,
                (__attribute__((address_space(3))) void*)(Bs + i * 2048 + wave * 512),
                16, 0, 0);
        }
    };

    const int kslot = lane >> 4;                     // which 8-wide k slice
    const int fr    = lane & 15;

    auto COMPUTE = [&](int d) {
        const uint16_t* As = lds + d * 8192;
        const uint16_t* Bs = lds + d * 8192 + 4096;
        bf16x8 af[4], bfr[4];
        #pragma unroll
        for (int mi = 0; mi < 4; ++mi) {
            const int r  = wm * 64 + mi * 16 + fr;
            const int ss = kslot ^ ((r >> 1) & 3);
            af[mi] = *(const bf16x8*)&As[r * 32 + ss * 8];
        }
        #pragma unroll
        for (int ni = 0; ni < 4; ++ni) {
            const int r  = wn * 64 + ni * 16 + fr;
            const int ss = kslot ^ ((r >> 1) & 3);
            bfr[ni] = *(const bf16x8*)&Bs[r * 32 + ss * 8];
        }
        #pragma unroll
        for (int mi = 0; mi < 4; ++mi)
            #pragma unroll
            for (int ni = 0; ni < 4; ++ni)
                acc[mi][ni] = __builtin_amdgcn_mfma_f32_16x16x32_bf16(
                    af[mi], bfr[ni], acc[mi][ni], 0, 0, 0);
    };

    STAGE(0, 0);
    STAGE(1, 1);
    for (int ks = 0; ks < 16; ++ks) {
        if (ks < 14) {
            STAGE(ks + 2, (ks + 2) % 3);
            asm volatile("s_waitcnt vmcnt(8)" ::: "memory");  // stage ks landed
        } else if (ks == 14) {
            asm volatile("s_waitcnt vmcnt(4)" ::: "memory");
        } else {
            asm volatile("s_waitcnt vmcnt(0)" ::: "memory");
        }
        __builtin_amdgcn_s_barrier();
        __builtin_amdgcn_sched_barrier(0);
        COMPUTE(ks % 3);
        __builtin_amdgcn_sched_barrier(0);
        __builtin_amdgcn_s_barrier();
    }

    // ---- epilogue: wave-private LDS transpose (aliased on buf 0; safe
    // after the loop's trailing barrier), coalesced 16B stores ----
    const int fq = lane >> 4;
    float bias[4];
    #pragma unroll
    for (int ni = 0; ni < 4; ++ni) {
        const int col = col0 + wn * 64 + ni * 16 + fr;
        bias[ni] = (col >= 512 && col < 1024) ? bk[col - 512] : 0.f;
    }
    const int rrow = lane >> 3;                      // 0..7   (read row)
    const int rcol = (lane & 7) * 8;                 // 0..56  (read col, 8 el)
    uint16_t* ep = lds + wave * 1152;                // 16*72 per wave
    #pragma unroll
    for (int mi = 0; mi < 4; ++mi) {
        #pragma unroll
        for (int ni = 0; ni < 4; ++ni)
            #pragma unroll
            for (int r4 = 0; r4 < 4; ++r4)
                ep[(fq * 4 + r4) * 72 + ni * 16 + fr] =
                    f2bf(acc[mi][ni][r4] + bias[ni]);
        __builtin_amdgcn_s_waitcnt(0);               // wave-local LDS drain
        #pragma unroll
        for (int it = 0; it < 2; ++it) {
            const int rl  = it * 8 + rrow;
            const int row = row0 + wm * 64 + mi * 16 + rl;
            u16x8 v = *(const u16x8*)&ep[rl * 72 + rcol];
            if (row < M_TOT)
                *(u16x8*)&y[(size_t)row * N3 + col0 + wn * 64 + rcol] = v;
        }
        __builtin_amdgcn_s_waitcnt(0);               // drain reads before reuse
    }
}

// ---------------------------------------------------------------------------
// attn: sliding-window over bf16 y. Thread = (b, c), strip of SCHUNK s.
// Ring of 8 q/v in registers: 3 new bf16 loads per s.
// ---------------------------------------------------------------------------
__global__ __launch_bounds__(512) void attn_kernel(
    const uint16_t* __restrict__ y, const float* __restrict__ pos,
    float* __restrict__ out)
{
    __shared__ float spos[DH_ * (NS_ + W_)];
    for (int i = threadIdx.x; i < DH_ * (NS_ + W_); i += 512) spos[i] = pos[i];
    __syncthreads();

    const int c  = threadIdx.x;                 // channel 0..511
    const int b  = blockIdx.y;
    const int s0 = blockIdx.x * SCHUNK;
    const uint16_t* yb = y + (size_t)b * T_ * N3;
    const int dh = c & (DH_ - 1);

    float pp[NS_ + W_];
    #pragma unroll
    for (int p = 0; p < NS_ + W_; ++p) pp[p] = spos[dh * (NS_ + W_) + p];

    const float sq0 = bf2f(yb[0 * N3 + c]),        sq1 = bf2f(yb[1 * N3 + c]);
    const float sv0 = bf2f(yb[0 * N3 + 1024 + c]), sv1 = bf2f(yb[1 * N3 + 1024 + c]);

    float qr[W_], vr[W_];
    #pragma unroll
    for (int j = 0; j < W_ - 1; ++j) {
        const uint16_t* rq = yb + (size_t)(NS_ + s0 + j) * N3 + c;
        qr[j] = bf2f(rq[0]);
        vr[j] = bf2f(rq[1024]);
    }

    for (int i = 0; i < SCHUNK; ++i) {
        const int s = s0 + i;
        int tq = NS_ + s + (W_ - 1);
        if (tq > T_ - 1) tq = T_ - 1;            // clamp (masked below)
        const uint16_t* rq = yb + (size_t)tq * N3 + c;
        qr[W_ - 1] = bf2f(rq[0]);
        vr[W_ - 1] = bf2f(rq[1024]);
        const float kv = bf2f(yb[(size_t)(NS_ + s) * N3 + 512 + c]);

        float sc[NS_ + W_];
        sc[0] = (sq0 + pp[0]) * kv;
        sc[1] = (sq1 + pp[1]) * kv;
        #pragma unroll
        for (int r = 0; r < W_; ++r) sc[NS_ + r] = (qr[r] + pp[NS_ + r]) * kv;
        if (s > S_ - W_) {                       // tail masking (uniform)
            const int nv = S_ - s;
            #pragma unroll
            for (int r = 0; r < W_; ++r)
                if (r >= nv) sc[NS_ + r] = -INFINITY;
        }

        float m = sc[0];
        #pragma unroll
        for (int p = 1; p < NS_ + W_; ++p) m = fmaxf(m, sc[p]);
        float e[NS_ + W_], sum = 0.f;
        #pragma unroll
        for (int p = 0; p < NS_ + W_; ++p) { e[p] = __expf(sc[p] - m); sum += e[p]; }
        float accv = e[0] * sv0 + e[1] * sv1;
        #pragma unroll
        for (int r = 0; r < W_; ++r) accv = fmaf(e[NS_ + r], vr[r], accv);

        out[((size_t)b * S_ + s) * DOUT_ + c] = accv / sum;

        #pragma unroll
        for (int j = 0; j < W_ - 1; ++j) { qr[j] = qr[j + 1]; vr[j] = vr[j + 1]; }
    }
}

// ---------------------------------------------------------------------------
extern "C" void kernel_launch(void* const* d_in, const int* in_sizes, int n_in,
                              void* d_out, int out_size, void* d_ws, size_t ws_size,
                              hipStream_t stream) {
    const float* x    = (const float*)d_in[0];
    const float* sink = (const float*)d_in[1];
    const float* Wk   = (const float*)d_in[2];
    const float* bk   = (const float*)d_in[3];
    const float* Wq   = (const float*)d_in[4];
    const float* Wv   = (const float*)d_in[5];
    const float* pos  = (const float*)d_in[6];

    char* ws = (char*)d_ws;
    uint16_t* y   = (uint16_t*)ws;                                // 25,190,400 B
    uint16_t* Abf = (uint16_t*)(ws + (size_t)M_TOT * N3 * 2);     //  8,519,680 B
    uint16_t* Bt  = (uint16_t*)(ws + (size_t)M_TOT * N3 * 2
                                   + (size_t)M_PAD * DM_ * 2);    //  1,572,864 B

    conv_fused<<<dim3(NBLK_A + 384), 256, 0, stream>>>(x, sink, Wq, Wk, Wv, Abf, Bt);
    gemm_bf16<<<dim3(N3 / 128, M_PAD / 128), 256, 0, stream>>>(Abf, Bt, bk, y);
    attn_kernel<<<dim3(S_ / SCHUNK, B_), 512, 0, stream>>>(y, pos, (float*)d_out);
}